// Round 9
// baseline (533.458 us; speedup 1.0000x reference)
//
#include <hip/hip_runtime.h>
#include <cstdint>
#include <cstddef>

#define DI __device__ __forceinline__

typedef _Float16 f16x8 __attribute__((ext_vector_type(8)));
typedef float f32x4 __attribute__((ext_vector_type(4)));

constexpr int Bb = 4, Ss = 4096, Cc = 256, Ee = 256;

// ---- ws layout (bytes); max 51,642,368 (< proven >=60MB) ----
constexpr size_t OFF_W   = 0;         // 384 KiB [3 mat][4 k0t][256 n][128B] fp16 W^T images
constexpr size_t OFF_Q   = 786432;    // 8 MiB [B*S][C] fp16
constexpr size_t OFF_K   = 9175040;   // 8 MiB [B][128 kt][16KB image] fp16
constexpr size_t OFF_V   = 17563648;  // 8 MiB [B][128 kt][16KB image] fp16
constexpr size_t OFF_PML = 25952256;  // 4*128KiB [z][b][qt][2][64] f32
// P1 partials (bf16, 8 MiB each for z=1..3) at OFF_PML + 4*131072.

DI unsigned bf_hi(float f) {
  unsigned u = __builtin_bit_cast(unsigned, f);
  return (u + 0x7fffu + ((u >> 16) & 1u)) >> 16;
}
DI float bf_f(unsigned h) { return __builtin_bit_cast(float, h << 16); }
DI unsigned short f16b(float v) {
  _Float16 h = (_Float16)v;  // RNE v_cvt_f16_f32
  return __builtin_bit_cast(unsigned short, h);
}
DI unsigned pk16rne(float a, float b) {  // RNE fp16 pair pack
  return (unsigned)f16b(a) | ((unsigned)f16b(b) << 16);
}
DI unsigned pkf16(float a, float b) {  // RTZ pack (P in [0,1]: bias negligible)
  return __builtin_bit_cast(unsigned, __builtin_amdgcn_cvt_pkrtz(a, b));
}
DI float uf(unsigned u) { return __builtin_bit_cast(float, u); }

DI f32x4 mfma16f(f16x8 a, f16x8 b, f32x4 c) {
  return __builtin_amdgcn_mfma_f32_16x16x32_f16(a, b, c, 0, 0, 0);
}

DI void gl16(const void* g, void* l) {
  __builtin_amdgcn_global_load_lds(
      (const __attribute__((address_space(1))) unsigned*)g,
      (__attribute__((address_space(3))) unsigned*)l, 16, 0, 0);
}

// K image: [32 rows][512B], byte = row*512 + ((col*2) ^ ((row&7)<<4))
// V image: [256 e][64B] packed 2 rows per 128B:
//   byte = (e>>1)*128 + (((e&1)*64 + k*2) ^ (((e>>1)&7)<<4))
// W image: per (mat,k0t): [256 n][128B], byte = n*128 + ((kin*2) ^ ((n&7)<<4))

// ---------------- W transpose -> fp16 swizzled images ----------------
// grid (4 kt, 4 nt, 3 mat), block 256.
__global__ __launch_bounds__(256) void k_transpose(
    const float* __restrict__ wq, const float* __restrict__ wk,
    const float* __restrict__ wv, char* __restrict__ wimg_all) {
  __shared__ float lds[64][65];
  const int t = threadIdx.x;
  const int kt = blockIdx.x, nt = blockIdx.y, mat = blockIdx.z;
  const float* src = mat == 0 ? wq : (mat == 1 ? wk : wv);
#pragma unroll
  for (int i = 0; i < 16; i++) {
    const int kr = i * 4 + (t >> 6);
    lds[kr][t & 63] = src[(size_t)(kt * 64 + kr) * Cc + nt * 64 + (t & 63)];
  }
  __syncthreads();
  char* wimg = wimg_all + (size_t)mat * 131072 + (size_t)kt * 32768;
  const int nl = t >> 2, qd = t & 3;
  const int n = nt * 64 + nl;
#pragma unroll
  for (int h = 0; h < 2; h++) {
    const int kl = qd * 16 + h * 8;
    uint4 pk = make_uint4(pk16rne(lds[kl + 0][nl], lds[kl + 1][nl]),
                          pk16rne(lds[kl + 2][nl], lds[kl + 3][nl]),
                          pk16rne(lds[kl + 4][nl], lds[kl + 5][nl]),
                          pk16rne(lds[kl + 6][nl], lds[kl + 7][nl]));
    *(uint4*)(wimg + n * 128 + ((qd * 32 + h * 16) ^ ((n & 7) << 4))) = pk;
  }
}

// ---------------- fused QKV projection (fp16, no LDS, no barriers) -------
// grid (256 m-tiles, 3 mat), block 256 (4 waves; wave w: 16 m-rows, full n).
// A-frags: x f32 -> fp16 RNE in-reg. B-frags: direct 16B reads of W image (L2).
__global__ __launch_bounds__(256, 2) void k_proj(
    const float* __restrict__ x, const float* __restrict__ bq,
    const float* __restrict__ bk, const float* __restrict__ bv,
    char* __restrict__ ws) {
  const int t = threadIdx.x, lane = t & 63, w = t >> 6;
  const int m0 = blockIdx.x * 64, mat = blockIdx.y;
  const float* bias = mat == 0 ? bq : (mat == 1 ? bk : bv);
  const char* wimg = ws + OFF_W + (size_t)mat * 131072;

  f32x4 acc[16];
#pragma unroll
  for (int f = 0; f < 16; f++) acc[f] = (f32x4){0.f, 0.f, 0.f, 0.f};

  const int mrow = m0 + w * 16 + (lane & 15);
  const float* xrow = x + (size_t)mrow * Cc;

  for (int k0t = 0; k0t < 4; k0t++) {
    const char* wk0 = wimg + k0t * 32768;
#pragma unroll
    for (int c2 = 0; c2 < 2; c2++) {
      const float* xk = xrow + k0t * 64 + c2 * 32 + (lane >> 4) * 8;
      uint4 a0 = *(const uint4*)(xk);
      uint4 a1 = *(const uint4*)(xk + 4);
      uint4 apk = make_uint4(pk16rne(uf(a0.x), uf(a0.y)),
                             pk16rne(uf(a0.z), uf(a0.w)),
                             pk16rne(uf(a1.x), uf(a1.y)),
                             pk16rne(uf(a1.z), uf(a1.w)));
      f16x8 af = __builtin_bit_cast(f16x8, apk);
#pragma unroll
      for (int f = 0; f < 16; f++) {
        const int n = f * 16 + (lane & 15);
        const int by = n * 128 + ((c2 * 64 + (lane >> 4) * 16) ^ ((n & 7) << 4));
        acc[f] = mfma16f(af, *(const f16x8*)(wk0 + by), acc[f]);
      }
    }
  }

  const int mgbase = m0 + w * 16 + (lane >> 4) * 4;
#pragma unroll
  for (int f = 0; f < 16; f++) {
    const int ncol = f * 16 + (lane & 15);
    const float bb = bias[ncol];
    if (mat == 0) {  // Q linear fp16
      unsigned short* qd = (unsigned short*)(ws + OFF_Q);
#pragma unroll
      for (int r = 0; r < 4; r++)
        qd[(size_t)(mgbase + r) * Cc + ncol] = f16b(acc[f][r] + bb);
    } else if (mat == 1) {  // K swizzled image fp16
      char* kf = ws + OFF_K;
#pragma unroll
      for (int r = 0; r < 4; r++) {
        const int mg = mgbase + r;
        const int bidx = mg >> 12, sg = mg & 4095;
        const int kt = sg >> 5, krow = sg & 31;
        const size_t base = ((size_t)(bidx * 128 + kt)) * 16384 +
                            (size_t)(krow * 512 + ((ncol * 2) ^ ((krow & 7) << 4)));
        *(unsigned short*)(kf + base) = f16b(acc[f][r] + bb);
      }
    } else {  // V swizzled image fp16
      char* vf = ws + OFF_V;
      unsigned short h[4];
#pragma unroll
      for (int r = 0; r < 4; r++) h[r] = f16b(acc[f][r] + bb);
      const int mg = mgbase;
      const int bidx = mg >> 12, sg = mg & 4095;
      const int kt = sg >> 5, kin = sg & 31;
      const int e = ncol;
      const size_t img = (size_t)((e >> 1) * 128 +
                         (((e & 1) * 64 + kin * 2) ^ (((e >> 1) & 7) << 4)));
      *(uint2*)(vf + ((size_t)(bidx * 128 + kt)) * 16384 + img) =
          make_uint2((unsigned)h[0] | ((unsigned)h[1] << 16),
                     (unsigned)h[2] | ((unsigned)h[3] << 16));
    }
  }
}

// ---------------- flash attention (fp16, kv-split, async-stage) ----------
// grid (64 qt, B, 4), block 256 (4 waves; wave w: q-rows w*16..+15, full e).
// KBLK=32. T14 stage split: next tile global->regs at iter top (latency
// hidden under compute), ds_write after the read-barrier. LDS 36KB (40KB
// granule) * 4 blocks/CU = 160KB exactly. Keep min-waves=2 (r5: (256,3)
// capped VGPR to 84 -> acc spilled, WRITE_SIZE 24->373MB).
__global__ __launch_bounds__(256, 2) void k_attn(
    char* __restrict__ ws, float* __restrict__ out, int nz) {
  __shared__ __align__(16) char sbuf[36864];  // 0:K 16K:V 32K:P(4x1K)
  const int t = threadIdx.x, lane = t & 63, w = t >> 6;
  const int qt = blockIdx.x, b = blockIdx.y, z = blockIdx.z;
  const int q0 = qt * 64;
  const int ktq = 128 / nz, ktr = 128 % nz;
  const int kt0 = z * ktq + (z < ktr ? z : ktr);
  const int cnt = ktq + (z < ktr ? 1 : 0);

  // ---- Q fragments (fp16) ----
  f16x8 qf[8];
  {
    const int qrow = q0 + w * 16 + (lane & 15);
    const unsigned short* qp =
        (const unsigned short*)(ws + OFF_Q) + (size_t)(b * Ss + qrow) * Cc;
#pragma unroll
    for (int c = 0; c < 8; c++)
      qf[c] = *(const f16x8*)(qp + c * 32 + (lane >> 4) * 8);
  }

  // ---- staging source offsets (linear: global layout == LDS image) ----
  unsigned srcoff[8];
#pragma unroll
  for (int j = 0; j < 8; j++) {
    const int L = w * 8192 + j * 1024;
    const unsigned rb = (L < 16384) ? (unsigned)OFF_K : (unsigned)OFF_V;
    srcoff[j] = rb + (unsigned)b * 2097152u + (unsigned)kt0 * 16384u +
                (unsigned)(L & 16383) + (unsigned)(lane * 16);
  }

  f32x4 acc[16];
#pragma unroll
  for (int eg = 0; eg < 16; eg++) acc[eg] = (f32x4){0.f, 0.f, 0.f, 0.f};
  float mrun[4] = {-1e30f, -1e30f, -1e30f, -1e30f};
  float lrun[4] = {0.f, 0.f, 0.f, 0.f};

  // ---- prologue: stage tile 0 via DMA ----
#pragma unroll
  for (int j = 0; j < 8; j++) gl16(ws + srcoff[j], sbuf + w * 8192 + j * 1024);
  __syncthreads();

  char* const phb = sbuf + 32768 + w * 1024;
  uint4 stg[8];

  for (int it = 0; it < cnt; it++) {
    const bool pf = (it + 1 < cnt);
    // ---- issue next-tile loads into regs (land during compute) ----
    if (pf) {
#pragma unroll
      for (int j = 0; j < 8; j++)
        stg[j] = *(const uint4*)(ws + srcoff[j] + 16384);
    }

    // ---- S = Q K^T (fp16) ----
    f32x4 sacc[2];
    sacc[0] = (f32x4){0.f, 0.f, 0.f, 0.f};
    sacc[1] = (f32x4){0.f, 0.f, 0.f, 0.f};
    __builtin_amdgcn_s_setprio(1);
#pragma unroll
    for (int c = 0; c < 8; c++) {
#pragma unroll
      for (int f = 0; f < 2; f++) {
        const int krow = f * 16 + (lane & 15);
        const int kby = krow * 512 + ((c * 64 + (lane >> 4) * 16) ^ ((krow & 7) << 4));
        sacc[f] = mfma16f(qf[c], *(const f16x8*)(sbuf + kby), sacc[f]);
      }
    }
    __builtin_amdgcn_s_setprio(0);

    // ---- online softmax with defer-max (rows q = (lane>>4)*4+r) ----
    float tm[4];
#pragma unroll
    for (int r = 0; r < 4; r++) tm[r] = fmaxf(sacc[0][r], sacc[1][r]);
#pragma unroll
    for (int r = 0; r < 4; r++) {
      tm[r] = fmaxf(tm[r], __shfl_xor(tm[r], 1, 64));
      tm[r] = fmaxf(tm[r], __shfl_xor(tm[r], 2, 64));
      tm[r] = fmaxf(tm[r], __shfl_xor(tm[r], 4, 64));
      tm[r] = fmaxf(tm[r], __shfl_xor(tm[r], 8, 64));
    }
    int ok = 1;
#pragma unroll
    for (int r = 0; r < 4; r++) ok &= (tm[r] <= mrun[r] + 5.5f) ? 1 : 0;
    if (!__all(ok)) {
      float sc[4];
#pragma unroll
      for (int r = 0; r < 4; r++) {
        float mn = fmaxf(mrun[r], tm[r]);
        sc[r] = __expf(mrun[r] - mn);
        mrun[r] = mn;
        lrun[r] *= sc[r];
      }
#pragma unroll
      for (int eg = 0; eg < 16; eg++) {
        acc[eg][0] *= sc[0]; acc[eg][1] *= sc[1];
        acc[eg][2] *= sc[2]; acc[eg][3] *= sc[3];
      }
    }
    float rsum[4] = {0.f, 0.f, 0.f, 0.f};
#pragma unroll
    for (int f = 0; f < 2; f++) {
#pragma unroll
      for (int r = 0; r < 4; r++) {
        float p = __expf(sacc[f][r] - mrun[r]);
        sacc[f][r] = p;
        rsum[r] += p;
      }
    }
#pragma unroll
    for (int r = 0; r < 4; r++) {
      rsum[r] += __shfl_xor(rsum[r], 1, 64);
      rsum[r] += __shfl_xor(rsum[r], 2, 64);
      rsum[r] += __shfl_xor(rsum[r], 4, 64);
      rsum[r] += __shfl_xor(rsum[r], 8, 64);
      lrun[r] += rsum[r];
    }

    // ---- P -> per-wave LDS (fp16, packed-row swizzle) ----
#pragma unroll
    for (int r = 0; r < 4; r++) {
      const unsigned wpk = pkf16(sacc[0][r], sacc[1][r]);
      const int q = (lane >> 4) * 4 + r;
      const int c0 = (lane & 15) * 2;
      const int lineb = (q >> 1) * 128, sw = ((q >> 1) & 7) << 4, half = (q & 1) * 64;
      *(unsigned short*)(phb + lineb + ((half + c0) ^ sw)) = (unsigned short)wpk;
      *(unsigned short*)(phb + lineb + ((half + 32 + c0) ^ sw)) =
          (unsigned short)(wpk >> 16);
    }

    // ---- O += P V (fp16) ----
    {
      const int q = lane & 15;
      const int pby = (q >> 1) * 128 +
                      (((q & 1) * 64 + (lane >> 4) * 16) ^ (((q >> 1) & 7) << 4));
      f16x8 pa = *(const f16x8*)(phb + pby);
      __builtin_amdgcn_s_setprio(1);
#pragma unroll
      for (int eg = 0; eg < 16; eg++) {
        const int erow = eg * 16 + (lane & 15);
        const int vby = (erow >> 1) * 128 +
                        (((erow & 1) * 64 + (lane >> 4) * 16) ^ (((erow >> 1) & 7) << 4));
        acc[eg] = mfma16f(pa, *(const f16x8*)(sbuf + 16384 + vby), acc[eg]);
      }
      __builtin_amdgcn_s_setprio(0);
    }

    __syncthreads();  // all reads of this tile done
    if (pf) {
#pragma unroll
      for (int j = 0; j < 8; j++) {
        srcoff[j] += 16384;
        *(uint4*)(sbuf + w * 8192 + j * 1024 + lane * 16) = stg[j];
      }
    }
    __syncthreads();  // next tile resident
  }

  // ---- epilogue: write partial (z0: f32 into out; z>=1: bf16) + m,l ----
  const int qloc0 = w * 16 + (lane >> 4) * 4;
  if (z == 0) {
#pragma unroll
    for (int eg = 0; eg < 16; eg++) {
      const int e = eg * 16 + (lane & 15);
#pragma unroll
      for (int r = 0; r < 4; r++)
        out[((size_t)(b * Ss + q0 + qloc0 + r)) * Ee + e] = acc[eg][r];
    }
  } else {
    unsigned short* p1 = (unsigned short*)(ws + OFF_PML + (size_t)nz * 131072 +
                                           (size_t)(z - 1) * 8388608);
#pragma unroll
    for (int eg = 0; eg < 16; eg++) {
      const int e = eg * 16 + (lane & 15);
#pragma unroll
      for (int r = 0; r < 4; r++)
        p1[((size_t)((b * 64 + qt) * 64 + qloc0 + r)) * 256 + e] =
            (unsigned short)bf_hi(acc[eg][r]);
    }
  }
  if ((lane & 15) == 0) {
    float* pml = (float*)(ws + OFF_PML);
#pragma unroll
    for (int r = 0; r < 4; r++) {
      const int q = qloc0 + r;
      pml[(((size_t)(z * 4 + b) * 64 + qt) * 2 + 0) * 64 + q] = mrun[r];
      pml[(((size_t)(z * 4 + b) * 64 + qt) * 2 + 1) * 64 + q] = lrun[r];
    }
  }
}

// ---------------- combine partials + sigmoid ----------------
// grid (64 qt, B, 4 qz), block 256 (thread = e; 16 q-rows per block).
__global__ __launch_bounds__(256) void k_comb(
    char* __restrict__ ws, float* __restrict__ out, int nz) {
  __shared__ float sm[4][16], sl[4][16];
  const int t = threadIdx.x, qt = blockIdx.x, b = blockIdx.y, qz = blockIdx.z;
  const float* pml = (const float*)(ws + OFF_PML);
  if (t < 16 * nz) {
    const int z = t >> 4, qq = t & 15;
    const int q = qz * 16 + qq;
    sm[z][qq] = pml[(((size_t)(z * 4 + b) * 64 + qt) * 2 + 0) * 64 + q];
    sl[z][qq] = pml[(((size_t)(z * 4 + b) * 64 + qt) * 2 + 1) * 64 + q];
  }
  __syncthreads();
  const unsigned short* p1 =
      (const unsigned short*)(ws + OFF_PML + (size_t)nz * 131072);
  for (int qi = 0; qi < 16; qi++) {
    const int q = qz * 16 + qi;
    const size_t o = ((size_t)(b * Ss + qt * 64 + q)) * Ee + t;
    float M = sm[0][qi];
    for (int z = 1; z < nz; z++) M = fmaxf(M, sm[z][qi]);
    float a0 = __expf(sm[0][qi] - M);
    float num = out[o] * a0, den = sl[0][qi] * a0;
    for (int z = 1; z < nz; z++) {
      float az = __expf(sm[z][qi] - M);
      float oz = bf_f(p1[(size_t)(z - 1) * 4194304 +
                         ((size_t)((b * 64 + qt) * 64 + q)) * 256 + t]);
      num += oz * az;
      den += sl[z][qi] * az;
    }
    float v = num / den;
    out[o] = 1.f / (1.f + __expf(-v));
  }
}

extern "C" void kernel_launch(void* const* d_in, const int* in_sizes, int n_in,
                              void* d_out, int out_size, void* d_ws, size_t ws_size,
                              hipStream_t stream) {
  (void)in_sizes; (void)n_in; (void)out_size; (void)ws_size;
  const float* x  = (const float*)d_in[0];
  const float* Wq = (const float*)d_in[1];
  const float* bq = (const float*)d_in[2];
  const float* Wk = (const float*)d_in[3];
  const float* bk = (const float*)d_in[4];
  const float* Wv = (const float*)d_in[5];
  const float* bv = (const float*)d_in[6];
  float* out = (float*)d_out;
  char* ws = (char*)d_ws;

  const int nz = 4;  // 1024 blocks = 4 blocks/CU x 40KB LDS = 160KB exactly

  hipLaunchKernelGGL(k_transpose, dim3(4, 4, 3), dim3(256), 0, stream,
                     Wq, Wk, Wv, ws + OFF_W);
  hipLaunchKernelGGL(k_proj, dim3(256, 3), dim3(256), 0, stream,
                     x, bq, bk, bv, ws);
  hipLaunchKernelGGL(k_attn, dim3(64, Bb, nz), dim3(256), 0, stream, ws, out, nz);
  hipLaunchKernelGGL(k_comb, dim3(64, Bb, 4), dim3(256), 0, stream, ws, out, nz);
}

// Round 10
// 280.498 us; speedup vs baseline: 1.9018x; 1.9018x over previous
//
#include <hip/hip_runtime.h>
#include <cstdint>
#include <cstddef>

#define DI __device__ __forceinline__

typedef _Float16 f16x8 __attribute__((ext_vector_type(8)));
typedef float f32x4 __attribute__((ext_vector_type(4)));

constexpr int Bb = 4, Ss = 4096, Cc = 256, Ee = 256;

// ---- ws layout (bytes); max 51,642,368 (nz=4 proven in r9) ----
constexpr size_t OFF_W   = 0;         // 384 KiB [3 mat][4 k0t][256 n][128B] fp16 W^T images
constexpr size_t OFF_Q   = 786432;    // 8 MiB [B*S][C] fp16
constexpr size_t OFF_K   = 9175040;   // 8 MiB [B][128 kt][16KB image] fp16
constexpr size_t OFF_V   = 17563648;  // 8 MiB [B][128 kt][16KB image] fp16
constexpr size_t OFF_PML = 25952256;  // 4*128KiB [z][b][qt][2][64] f32
// P1 partials (bf16, 8 MiB each for z=1..3) at OFF_PML + 4*131072.

DI unsigned bf_hi(float f) {
  unsigned u = __builtin_bit_cast(unsigned, f);
  return (u + 0x7fffu + ((u >> 16) & 1u)) >> 16;
}
DI float bf_f(unsigned h) { return __builtin_bit_cast(float, h << 16); }
DI unsigned short f16b(float v) {
  _Float16 h = (_Float16)v;  // RNE v_cvt_f16_f32
  return __builtin_bit_cast(unsigned short, h);
}
DI unsigned pk16rne(float a, float b) {  // RNE fp16 pair pack
  return (unsigned)f16b(a) | ((unsigned)f16b(b) << 16);
}
DI unsigned pkf16(float a, float b) {  // RTZ pack (P in [0,1]: bias negligible)
  return __builtin_bit_cast(unsigned, __builtin_amdgcn_cvt_pkrtz(a, b));
}
DI float uf(unsigned u) { return __builtin_bit_cast(float, u); }

DI f32x4 mfma16f(f16x8 a, f16x8 b, f32x4 c) {
  return __builtin_amdgcn_mfma_f32_16x16x32_f16(a, b, c, 0, 0, 0);
}

DI void gl16(const void* g, void* l) {
  __builtin_amdgcn_global_load_lds(
      (const __attribute__((address_space(1))) unsigned*)g,
      (__attribute__((address_space(3))) unsigned*)l, 16, 0, 0);
}

// K image: [32 rows][512B], byte = row*512 + ((col*2) ^ ((row&7)<<4))
// V image: [256 e][64B] packed 2 rows per 128B:
//   byte = (e>>1)*128 + (((e&1)*64 + k*2) ^ (((e>>1)&7)<<4))
// W image: per (mat,k0t): [256 n][128B], byte = n*128 + ((kin*2) ^ ((n&7)<<4))

// ---------------- W transpose -> fp16 swizzled images ----------------
// grid (4 kt, 4 nt, 3 mat), block 256.
__global__ __launch_bounds__(256) void k_transpose(
    const float* __restrict__ wq, const float* __restrict__ wk,
    const float* __restrict__ wv, char* __restrict__ wimg_all) {
  __shared__ float lds[64][65];
  const int t = threadIdx.x;
  const int kt = blockIdx.x, nt = blockIdx.y, mat = blockIdx.z;
  const float* src = mat == 0 ? wq : (mat == 1 ? wk : wv);
#pragma unroll
  for (int i = 0; i < 16; i++) {
    const int kr = i * 4 + (t >> 6);
    lds[kr][t & 63] = src[(size_t)(kt * 64 + kr) * Cc + nt * 64 + (t & 63)];
  }
  __syncthreads();
  char* wimg = wimg_all + (size_t)mat * 131072 + (size_t)kt * 32768;
  const int nl = t >> 2, qd = t & 3;
  const int n = nt * 64 + nl;
#pragma unroll
  for (int h = 0; h < 2; h++) {
    const int kl = qd * 16 + h * 8;
    uint4 pk = make_uint4(pk16rne(lds[kl + 0][nl], lds[kl + 1][nl]),
                          pk16rne(lds[kl + 2][nl], lds[kl + 3][nl]),
                          pk16rne(lds[kl + 4][nl], lds[kl + 5][nl]),
                          pk16rne(lds[kl + 6][nl], lds[kl + 7][nl]));
    *(uint4*)(wimg + n * 128 + ((qd * 32 + h * 16) ^ ((n & 7) << 4))) = pk;
  }
}

// ---------------- fused QKV projection (fp16, no LDS, no barriers) -------
// grid (256 m-tiles, 3 mat), block 256 (4 waves; wave w: 16 m-rows, full n).
// A-frags: x f32 -> fp16 RNE in-reg. B-frags: direct 16B reads of W image (L2).
__global__ __launch_bounds__(256, 2) void k_proj(
    const float* __restrict__ x, const float* __restrict__ bq,
    const float* __restrict__ bk, const float* __restrict__ bv,
    char* __restrict__ ws) {
  const int t = threadIdx.x, lane = t & 63, w = t >> 6;
  const int m0 = blockIdx.x * 64, mat = blockIdx.y;
  const float* bias = mat == 0 ? bq : (mat == 1 ? bk : bv);
  const char* wimg = ws + OFF_W + (size_t)mat * 131072;

  f32x4 acc[16];
#pragma unroll
  for (int f = 0; f < 16; f++) acc[f] = (f32x4){0.f, 0.f, 0.f, 0.f};

  const int mrow = m0 + w * 16 + (lane & 15);
  const float* xrow = x + (size_t)mrow * Cc;

  for (int k0t = 0; k0t < 4; k0t++) {
    const char* wk0 = wimg + k0t * 32768;
#pragma unroll
    for (int c2 = 0; c2 < 2; c2++) {
      const float* xk = xrow + k0t * 64 + c2 * 32 + (lane >> 4) * 8;
      uint4 a0 = *(const uint4*)(xk);
      uint4 a1 = *(const uint4*)(xk + 4);
      uint4 apk = make_uint4(pk16rne(uf(a0.x), uf(a0.y)),
                             pk16rne(uf(a0.z), uf(a0.w)),
                             pk16rne(uf(a1.x), uf(a1.y)),
                             pk16rne(uf(a1.z), uf(a1.w)));
      f16x8 af = __builtin_bit_cast(f16x8, apk);
#pragma unroll
      for (int f = 0; f < 16; f++) {
        const int n = f * 16 + (lane & 15);
        const int by = n * 128 + ((c2 * 64 + (lane >> 4) * 16) ^ ((n & 7) << 4));
        acc[f] = mfma16f(af, *(const f16x8*)(wk0 + by), acc[f]);
      }
    }
  }

  const int mgbase = m0 + w * 16 + (lane >> 4) * 4;
#pragma unroll
  for (int f = 0; f < 16; f++) {
    const int ncol = f * 16 + (lane & 15);
    const float bb = bias[ncol];
    if (mat == 0) {  // Q linear fp16
      unsigned short* qd = (unsigned short*)(ws + OFF_Q);
#pragma unroll
      for (int r = 0; r < 4; r++)
        qd[(size_t)(mgbase + r) * Cc + ncol] = f16b(acc[f][r] + bb);
    } else if (mat == 1) {  // K swizzled image fp16
      char* kf = ws + OFF_K;
#pragma unroll
      for (int r = 0; r < 4; r++) {
        const int mg = mgbase + r;
        const int bidx = mg >> 12, sg = mg & 4095;
        const int kt = sg >> 5, krow = sg & 31;
        const size_t base = ((size_t)(bidx * 128 + kt)) * 16384 +
                            (size_t)(krow * 512 + ((ncol * 2) ^ ((krow & 7) << 4)));
        *(unsigned short*)(kf + base) = f16b(acc[f][r] + bb);
      }
    } else {  // V swizzled image fp16
      char* vf = ws + OFF_V;
      unsigned short h[4];
#pragma unroll
      for (int r = 0; r < 4; r++) h[r] = f16b(acc[f][r] + bb);
      const int mg = mgbase;
      const int bidx = mg >> 12, sg = mg & 4095;
      const int kt = sg >> 5, kin = sg & 31;
      const int e = ncol;
      const size_t img = (size_t)((e >> 1) * 128 +
                         (((e & 1) * 64 + kin * 2) ^ (((e >> 1) & 7) << 4)));
      *(uint2*)(vf + ((size_t)(bidx * 128 + kt)) * 16384 + img) =
          make_uint2((unsigned)h[0] | ((unsigned)h[1] << 16),
                     (unsigned)h[2] | ((unsigned)h[3] << 16));
    }
  }
}

// ---------------- flash attention (fp16, kv-split, DMA staging) ----------
// grid (64 qt, B, 4), block 256 (4 waves; wave w: q-rows w*16..+15, full e).
// KBLK=32, single-buffered K/V via global_load_lds (r8-proven structure).
// NOTE r9 lesson: reg-staging (uint4 stg[8]) overflows the VGPR budget the
// allocator picks for this LDS shape -> acc spills to scratch (WRITE 651MB).
// Staging must stay on the DMA path. NOTE r5 lesson: keep min-waves=2.
__global__ __launch_bounds__(256, 2) void k_attn(
    char* __restrict__ ws, float* __restrict__ out, int nz) {
  __shared__ __align__(16) char sbuf[36864];  // 0:K 16K:V 32K:P(4x1K)
  const int t = threadIdx.x, lane = t & 63, w = t >> 6;
  const int qt = blockIdx.x, b = blockIdx.y, z = blockIdx.z;
  const int q0 = qt * 64;
  const int ktq = 128 / nz, ktr = 128 % nz;
  const int kt0 = z * ktq + (z < ktr ? z : ktr);
  const int cnt = ktq + (z < ktr ? 1 : 0);

  // ---- Q fragments (fp16) ----
  f16x8 qf[8];
  {
    const int qrow = q0 + w * 16 + (lane & 15);
    const unsigned short* qp =
        (const unsigned short*)(ws + OFF_Q) + (size_t)(b * Ss + qrow) * Cc;
#pragma unroll
    for (int c = 0; c < 8; c++)
      qf[c] = *(const f16x8*)(qp + c * 32 + (lane >> 4) * 8);
  }

  // ---- staging source offsets (linear: global layout == LDS image) ----
  unsigned srcoff[8];
#pragma unroll
  for (int j = 0; j < 8; j++) {
    const int L = w * 8192 + j * 1024;
    const unsigned rb = (L < 16384) ? (unsigned)OFF_K : (unsigned)OFF_V;
    srcoff[j] = rb + (unsigned)b * 2097152u + (unsigned)kt0 * 16384u +
                (unsigned)(L & 16383) + (unsigned)(lane * 16);
  }

  f32x4 acc[16];
#pragma unroll
  for (int eg = 0; eg < 16; eg++) acc[eg] = (f32x4){0.f, 0.f, 0.f, 0.f};
  float mrun[4] = {-1e30f, -1e30f, -1e30f, -1e30f};
  float lrun[4] = {0.f, 0.f, 0.f, 0.f};

  // ---- prologue: stage tile 0 via DMA ----
#pragma unroll
  for (int j = 0; j < 8; j++) gl16(ws + srcoff[j], sbuf + w * 8192 + j * 1024);
  __syncthreads();

  char* const phb = sbuf + 32768 + w * 1024;

  for (int it = 0; it < cnt; it++) {
    // ---- S = Q K^T (fp16) ----
    f32x4 sacc[2];
    sacc[0] = (f32x4){0.f, 0.f, 0.f, 0.f};
    sacc[1] = (f32x4){0.f, 0.f, 0.f, 0.f};
    __builtin_amdgcn_s_setprio(1);
#pragma unroll
    for (int c = 0; c < 8; c++) {
#pragma unroll
      for (int f = 0; f < 2; f++) {
        const int krow = f * 16 + (lane & 15);
        const int kby = krow * 512 + ((c * 64 + (lane >> 4) * 16) ^ ((krow & 7) << 4));
        sacc[f] = mfma16f(qf[c], *(const f16x8*)(sbuf + kby), sacc[f]);
      }
    }
    __builtin_amdgcn_s_setprio(0);

    // ---- online softmax with defer-max (rows q = (lane>>4)*4+r) ----
    float tm[4];
#pragma unroll
    for (int r = 0; r < 4; r++) tm[r] = fmaxf(sacc[0][r], sacc[1][r]);
#pragma unroll
    for (int r = 0; r < 4; r++) {
      tm[r] = fmaxf(tm[r], __shfl_xor(tm[r], 1, 64));
      tm[r] = fmaxf(tm[r], __shfl_xor(tm[r], 2, 64));
      tm[r] = fmaxf(tm[r], __shfl_xor(tm[r], 4, 64));
      tm[r] = fmaxf(tm[r], __shfl_xor(tm[r], 8, 64));
    }
    int ok = 1;
#pragma unroll
    for (int r = 0; r < 4; r++) ok &= (tm[r] <= mrun[r] + 5.5f) ? 1 : 0;
    if (!__all(ok)) {
      float sc[4];
#pragma unroll
      for (int r = 0; r < 4; r++) {
        float mn = fmaxf(mrun[r], tm[r]);
        sc[r] = __expf(mrun[r] - mn);
        mrun[r] = mn;
        lrun[r] *= sc[r];
      }
#pragma unroll
      for (int eg = 0; eg < 16; eg++) {
        acc[eg][0] *= sc[0]; acc[eg][1] *= sc[1];
        acc[eg][2] *= sc[2]; acc[eg][3] *= sc[3];
      }
    }
    float rsum[4] = {0.f, 0.f, 0.f, 0.f};
#pragma unroll
    for (int f = 0; f < 2; f++) {
#pragma unroll
      for (int r = 0; r < 4; r++) {
        float p = __expf(sacc[f][r] - mrun[r]);
        sacc[f][r] = p;
        rsum[r] += p;
      }
    }
#pragma unroll
    for (int r = 0; r < 4; r++) {
      rsum[r] += __shfl_xor(rsum[r], 1, 64);
      rsum[r] += __shfl_xor(rsum[r], 2, 64);
      rsum[r] += __shfl_xor(rsum[r], 4, 64);
      rsum[r] += __shfl_xor(rsum[r], 8, 64);
      lrun[r] += rsum[r];
    }

    // ---- P -> per-wave LDS (fp16, packed-row swizzle) ----
#pragma unroll
    for (int r = 0; r < 4; r++) {
      const unsigned wpk = pkf16(sacc[0][r], sacc[1][r]);
      const int q = (lane >> 4) * 4 + r;
      const int c0 = (lane & 15) * 2;
      const int lineb = (q >> 1) * 128, sw = ((q >> 1) & 7) << 4, half = (q & 1) * 64;
      *(unsigned short*)(phb + lineb + ((half + c0) ^ sw)) = (unsigned short)wpk;
      *(unsigned short*)(phb + lineb + ((half + 32 + c0) ^ sw)) =
          (unsigned short)(wpk >> 16);
    }

    // ---- O += P V (fp16) ----
    {
      const int q = lane & 15;
      const int pby = (q >> 1) * 128 +
                      (((q & 1) * 64 + (lane >> 4) * 16) ^ (((q >> 1) & 7) << 4));
      f16x8 pa = *(const f16x8*)(phb + pby);
      __builtin_amdgcn_s_setprio(1);
#pragma unroll
      for (int eg = 0; eg < 16; eg++) {
        const int erow = eg * 16 + (lane & 15);
        const int vby = (erow >> 1) * 128 +
                        (((erow & 1) * 64 + (lane >> 4) * 16) ^ (((erow >> 1) & 7) << 4));
        acc[eg] = mfma16f(pa, *(const f16x8*)(sbuf + 16384 + vby), acc[eg]);
      }
      __builtin_amdgcn_s_setprio(0);
    }

    __syncthreads();  // all reads of this tile done
    if (it + 1 < cnt) {
#pragma unroll
      for (int j = 0; j < 8; j++) {
        srcoff[j] += 16384;
        gl16(ws + srcoff[j], sbuf + w * 8192 + j * 1024);
      }
    }
    __syncthreads();  // vmcnt(0) drain: next tile resident
  }

  // ---- epilogue: write partial (z0: f32 into out; z>=1: bf16) + m,l ----
  const int qloc0 = w * 16 + (lane >> 4) * 4;
  if (z == 0) {
#pragma unroll
    for (int eg = 0; eg < 16; eg++) {
      const int e = eg * 16 + (lane & 15);
#pragma unroll
      for (int r = 0; r < 4; r++)
        out[((size_t)(b * Ss + q0 + qloc0 + r)) * Ee + e] = acc[eg][r];
    }
  } else {
    unsigned short* p1 = (unsigned short*)(ws + OFF_PML + (size_t)nz * 131072 +
                                           (size_t)(z - 1) * 8388608);
#pragma unroll
    for (int eg = 0; eg < 16; eg++) {
      const int e = eg * 16 + (lane & 15);
#pragma unroll
      for (int r = 0; r < 4; r++)
        p1[((size_t)((b * 64 + qt) * 64 + qloc0 + r)) * 256 + e] =
            (unsigned short)bf_hi(acc[eg][r]);
    }
  }
  if ((lane & 15) == 0) {
    float* pml = (float*)(ws + OFF_PML);
#pragma unroll
    for (int r = 0; r < 4; r++) {
      const int q = qloc0 + r;
      pml[(((size_t)(z * 4 + b) * 64 + qt) * 2 + 0) * 64 + q] = mrun[r];
      pml[(((size_t)(z * 4 + b) * 64 + qt) * 2 + 1) * 64 + q] = lrun[r];
    }
  }
}

// ---------------- combine partials + sigmoid ----------------
// grid (64 qt, B, 4 qz), block 256 (thread = e; 16 q-rows per block).
__global__ __launch_bounds__(256) void k_comb(
    char* __restrict__ ws, float* __restrict__ out, int nz) {
  __shared__ float sm[4][16], sl[4][16];
  const int t = threadIdx.x, qt = blockIdx.x, b = blockIdx.y, qz = blockIdx.z;
  const float* pml = (const float*)(ws + OFF_PML);
  if (t < 16 * nz) {
    const int z = t >> 4, qq = t & 15;
    const int q = qz * 16 + qq;
    sm[z][qq] = pml[(((size_t)(z * 4 + b) * 64 + qt) * 2 + 0) * 64 + q];
    sl[z][qq] = pml[(((size_t)(z * 4 + b) * 64 + qt) * 2 + 1) * 64 + q];
  }
  __syncthreads();
  const unsigned short* p1 =
      (const unsigned short*)(ws + OFF_PML + (size_t)nz * 131072);
  for (int qi = 0; qi < 16; qi++) {
    const int q = qz * 16 + qi;
    const size_t o = ((size_t)(b * Ss + qt * 64 + q)) * Ee + t;
    float M = sm[0][qi];
    for (int z = 1; z < nz; z++) M = fmaxf(M, sm[z][qi]);
    float a0 = __expf(sm[0][qi] - M);
    float num = out[o] * a0, den = sl[0][qi] * a0;
    for (int z = 1; z < nz; z++) {
      float az = __expf(sm[z][qi] - M);
      float oz = bf_f(p1[(size_t)(z - 1) * 4194304 +
                         ((size_t)((b * 64 + qt) * 64 + q)) * 256 + t]);
      num += oz * az;
      den += sl[z][qi] * az;
    }
    float v = num / den;
    out[o] = 1.f / (1.f + __expf(-v));
  }
}

extern "C" void kernel_launch(void* const* d_in, const int* in_sizes, int n_in,
                              void* d_out, int out_size, void* d_ws, size_t ws_size,
                              hipStream_t stream) {
  (void)in_sizes; (void)n_in; (void)out_size; (void)ws_size;
  const float* x  = (const float*)d_in[0];
  const float* Wq = (const float*)d_in[1];
  const float* bq = (const float*)d_in[2];
  const float* Wk = (const float*)d_in[3];
  const float* bk = (const float*)d_in[4];
  const float* Wv = (const float*)d_in[5];
  const float* bv = (const float*)d_in[6];
  float* out = (float*)d_out;
  char* ws = (char*)d_ws;

  const int nz = 4;  // 1024 blocks = 4 blocks/CU x 40KB-granule LDS = 160KB

  hipLaunchKernelGGL(k_transpose, dim3(4, 4, 3), dim3(256), 0, stream,
                     Wq, Wk, Wv, ws + OFF_W);
  hipLaunchKernelGGL(k_proj, dim3(256, 3), dim3(256), 0, stream,
                     x, bq, bk, bv, ws);
  hipLaunchKernelGGL(k_attn, dim3(64, Bb, nz), dim3(256), 0, stream, ws, out, nz);
  hipLaunchKernelGGL(k_comb, dim3(64, Bb, 4), dim3(256), 0, stream, ws, out, nz);
}